// Round 7
// baseline (90.160 us; speedup 1.0000x reference)
//
#include <hip/hip_runtime.h>
#include <hip/hip_bf16.h>

#define NTOK  2048          // F*H*W = 2*32*32
#define INNER 512
#define KDIM  512
#define QKVP  1536          // qkv row pitch (bf16 elems)

typedef __attribute__((ext_vector_type(8))) short bf16x8;
typedef __attribute__((ext_vector_type(4))) float f32x4;

// fp32 -> bf16 bits, round-to-nearest-even
__device__ __forceinline__ unsigned short f2b(float f) {
  unsigned int u = __float_as_uint(f);
  return (unsigned short)((u + 0x7FFFu + ((u >> 16) & 1u)) >> 16);
}

// async global->LDS, 16 bytes per lane (wave-linear LDS mapping required)
__device__ __forceinline__ void async_copy16(const unsigned short* g, unsigned short* l) {
  __builtin_amdgcn_global_load_lds((const __attribute__((address_space(1))) void*)g,
                                   (__attribute__((address_space(3))) void*)l, 16, 0, 0);
}

// ---------------- prep: weight transposes + x conversion + neighbor lists ----------------
// blocks 0..767:    w_qkv [512][1536] -> wqkvT [1536][512] bf16
// blocks 768..1023: w_out [512][512]  -> woutT [512][512]  bf16
// blocks 1024..1151: packed causal key list for tile pt = b-1024
// blocks 1152..2175: x fp32 -> xb bf16 (4 elems/thread)
__global__ __launch_bounds__(256) void prep(const float* __restrict__ w_qkv,
                                            const float* __restrict__ w_out,
                                            const float* __restrict__ x,
                                            unsigned short* __restrict__ wqkvT,
                                            unsigned short* __restrict__ woutT,
                                            unsigned short* __restrict__ xb,
                                            int* __restrict__ glist,
                                            int* __restrict__ gcnt) {
  __shared__ float tile[32][33];
  __shared__ int list[192];
  __shared__ int cntS;
  const int tid = threadIdx.x;
  int b = blockIdx.x;

  if (b >= 1152) {  // x conversion
    const int i = (b - 1152) * 1024 + tid * 4;
    float4 v = *(const float4*)(x + i);
    ushort4 o;
    o.x = f2b(v.x); o.y = f2b(v.y); o.z = f2b(v.z); o.w = f2b(v.w);
    *(ushort4*)(xb + i) = o;
    return;
  }

  if (b < 1024) {  // weight transpose
    const float* in; unsigned short* out; int K, N, bx, by;
    if (b < 768) { in = w_qkv; out = wqkvT; K = 512; N = 1536; bx = b % 48; by = b / 48; }
    else { int bb = b - 768; in = w_out; out = woutT; K = 512; N = 512; bx = bb & 15; by = bb >> 4; }
    const int k0 = by * 32, n0 = bx * 32;
    const int r = tid >> 3, c4 = (tid & 7) * 4;
    float4 v = *(const float4*)(in + (size_t)(k0 + r) * N + n0 + c4);
    tile[r][c4 + 0] = v.x; tile[r][c4 + 1] = v.y;
    tile[r][c4 + 2] = v.z; tile[r][c4 + 3] = v.w;
    __syncthreads();
    ushort4 o;
    o.x = f2b(tile[c4 + 0][r]);
    o.y = f2b(tile[c4 + 1][r]);
    o.z = f2b(tile[c4 + 2][r]);
    o.w = f2b(tile[c4 + 3][r]);
    *(ushort4*)(out + (size_t)(n0 + r) * K + k0 + c4) = o;
    return;
  }

  // ---- neighbor list for one 16-w tile ----
  const int pt = b - 1024;
  const int f  = pt >> 6;
  const int hh = (pt >> 1) & 31;
  const int w0 = (pt & 1) << 4;

  if (tid < 192) list[tid] = 0x7FFFFFFF;
  if (tid == 0) { list[0] = 0; cntS = 1; }
  __syncthreads();
  if (tid >= 1 && tid <= 160) {
    int cc = tid - 1;
    int p = cc / 20, wo = cc - p * 20;
    int ff = (p < 5) ? 0 : 1;
    int h2 = hh - 2 + ((p < 5) ? p : (p - 5));
    bool ok = (p < 5) ? ((f == 1) ? (h2 >= 0 && h2 <= 31) : (p <= 2 && h2 >= 0))
                      : (f == 1 && h2 >= 0);
    if (ok) {
      bool diag = (ff == f) && (h2 == hh);
      int wlo = max(0, w0 - 2);
      int whi = min(31, diag ? (w0 + 15) : (w0 + 17));
      int w2 = wlo + wo;
      if (w2 <= whi) {
        int pos = atomicAdd(&cntS, 1);
        list[pos] = ((ff << 10) | (h2 << 5) | w2) + 1;
      }
    }
  }
  __syncthreads();
  if (tid < 192) glist[pt * 192 + tid] = list[tid];
  if (tid == 0) gcnt[pt] = cntS;
}

// ---------------- GEMM1: qkv = xb @ wqkvT^T -> bf16 ----------------
// BM=64, BN=64, BK=64; 2-deep counted-vmcnt pipeline (round-6 verified). 768 blocks,
// 1-D grid with bijective XCD-rectangle swizzle: XCD (bid&7) owns an 8m x 12n
// rectangle -> per-XCD cold fetch ~1.3MB (A 512KB + B 768KB) instead of ~2.2MB.
__global__ __launch_bounds__(256, 4) void gemm_qkv(const unsigned short* __restrict__ A,
                                                   const unsigned short* __restrict__ Bt,
                                                   unsigned short* __restrict__ C) {
  constexpr int N = 1536, K = 512;
  __shared__ __align__(16) unsigned short As[2][2][64 * 32];   // [buf][half]
  __shared__ __align__(16) unsigned short Bs[2][2][64 * 32];
  const int tid = threadIdx.x, lane = tid & 63, wave = tid >> 6;
  const int bid = blockIdx.x;
  const int xcd = bid & 7, idx = bid >> 3;       // idx 0..95
  const int rm = idx & 7, rn = idx >> 3;         // 8 x 12 rectangle
  const int m0 = (((xcd >> 1) << 3) + rm) * 64;  // m-panel 0..31
  const int n0 = ((xcd & 1) * 12 + rn) * 64;     // n-panel 0..23
  const int wm = (wave >> 1) * 32, wn = (wave & 1) * 32;
  const int li = tid * 8, r = li >> 5, c = li & 31;   // 64x32 sub-tile: 8 elems/thread
  const int fr = lane & 15, fk = (lane >> 4) * 8;

  f32x4 acc[2][2] = {};

#define STG1(buf, kk)                                                              \
  do {                                                                             \
    async_copy16(A  + (size_t)(m0 + r) * K + (kk) + c,      &As[buf][0][li]);      \
    async_copy16(A  + (size_t)(m0 + r) * K + (kk) + 32 + c, &As[buf][1][li]);      \
    async_copy16(Bt + (size_t)(n0 + r) * K + (kk) + c,      &Bs[buf][0][li]);      \
    async_copy16(Bt + (size_t)(n0 + r) * K + (kk) + 32 + c, &Bs[buf][1][li]);      \
  } while (0)

  STG1(0, 0);
#pragma unroll
  for (int it = 0; it < 8; ++it) {
    const int cur = it & 1;
    if (it < 7) {
      STG1(cur ^ 1, (it + 1) * 64);
      asm volatile("s_waitcnt vmcnt(4)" ::: "memory");   // drain tile it, keep it+1 in flight
    } else {
      asm volatile("s_waitcnt vmcnt(0)" ::: "memory");
    }
    __builtin_amdgcn_s_barrier();        // all waves' tile-it stages now landed
    __builtin_amdgcn_sched_barrier(0);   // don't hoist ds_reads above the wait
    bf16x8 af[2][2], bfr[2][2];
#pragma unroll
    for (int h = 0; h < 2; ++h) {
#pragma unroll
      for (int i = 0; i < 2; ++i) af[i][h]  = *(const bf16x8*)&As[cur][h][(wm + i * 16 + fr) * 32 + fk];
#pragma unroll
      for (int j = 0; j < 2; ++j) bfr[j][h] = *(const bf16x8*)&Bs[cur][h][(wn + j * 16 + fr) * 32 + fk];
    }
#pragma unroll
    for (int i = 0; i < 2; ++i)
#pragma unroll
      for (int j = 0; j < 2; ++j) {
        acc[i][j] = __builtin_amdgcn_mfma_f32_16x16x32_bf16(af[i][0], bfr[j][0], acc[i][j], 0, 0, 0);
        acc[i][j] = __builtin_amdgcn_mfma_f32_16x16x32_bf16(af[i][1], bfr[j][1], acc[i][j], 0, 0, 0);
      }
    __builtin_amdgcn_s_barrier();        // all reads of buf cur done before it+2 overwrites
  }
#undef STG1

  const int er = (lane >> 4) * 4, ec = lane & 15;
#pragma unroll
  for (int i = 0; i < 2; ++i)
#pragma unroll
    for (int j = 0; j < 2; ++j) {
      const int col = n0 + wn + j * 16 + ec;
#pragma unroll
      for (int rr = 0; rr < 4; ++rr) {
        const int row = m0 + wm + i * 16 + er + rr;
        C[(size_t)row * N + col] = f2b(acc[i][j][rr]);
      }
    }
}

// ---------------- GEMM2: out = Ob @ woutT^T + bias -> fp32 ----------------
// BM=32, BN=64, BK=64; 2-deep counted-vmcnt pipeline. 512 blocks, 1-D grid with
// bijective XCD-rectangle swizzle (16m x 4n per XCD).
__global__ __launch_bounds__(256, 4) void gemm_out(const unsigned short* __restrict__ A,
                                                   const unsigned short* __restrict__ Bt,
                                                   const float* __restrict__ bias,
                                                   float* __restrict__ C) {
  constexpr int N = 512, K = 512;
  __shared__ __align__(16) unsigned short As[2][2][32 * 32];
  __shared__ __align__(16) unsigned short Bs[2][2][64 * 32];
  const int tid = threadIdx.x, lane = tid & 63, wave = tid >> 6;
  const int bid = blockIdx.x;
  const int xcd = bid & 7, idx = bid >> 3;        // idx 0..63
  const int rm = idx & 15, rn = idx >> 4;         // 16 x 4 rectangle
  const int m0 = (((xcd >> 1) << 4) + rm) * 32;   // m-panel 0..63
  const int n0 = ((xcd & 1) * 4 + rn) * 64;       // n-panel 0..7
  const int wm = (wave >> 1) * 16, wn = (wave & 1) * 32;
  const int li = tid * 8, r = li >> 5, c = li & 31;
  const int fr = lane & 15, fk = (lane >> 4) * 8;

  f32x4 acc[2] = {};

#define STG2(buf, kk)                                                               \
  do {                                                                              \
    if (tid < 128) {                                                                \
      async_copy16(A + (size_t)(m0 + r) * K + (kk) + c,      &As[buf][0][li]);      \
      async_copy16(A + (size_t)(m0 + r) * K + (kk) + 32 + c, &As[buf][1][li]);      \
    }                                                                               \
    async_copy16(Bt + (size_t)(n0 + r) * K + (kk) + c,      &Bs[buf][0][li]);       \
    async_copy16(Bt + (size_t)(n0 + r) * K + (kk) + 32 + c, &Bs[buf][1][li]);       \
  } while (0)

  STG2(0, 0);
#pragma unroll
  for (int it = 0; it < 8; ++it) {
    const int cur = it & 1;
    if (it < 7) {
      STG2(cur ^ 1, (it + 1) * 64);
      if (wave < 2) asm volatile("s_waitcnt vmcnt(4)" ::: "memory");
      else          asm volatile("s_waitcnt vmcnt(2)" ::: "memory");
    } else {
      asm volatile("s_waitcnt vmcnt(0)" ::: "memory");
    }
    __builtin_amdgcn_s_barrier();
    __builtin_amdgcn_sched_barrier(0);
    bf16x8 af[2], bfr[2][2];
#pragma unroll
    for (int h = 0; h < 2; ++h) {
      af[h] = *(const bf16x8*)&As[cur][h][(wm + fr) * 32 + fk];
#pragma unroll
      for (int j = 0; j < 2; ++j) bfr[j][h] = *(const bf16x8*)&Bs[cur][h][(wn + j * 16 + fr) * 32 + fk];
    }
#pragma unroll
    for (int j = 0; j < 2; ++j) {
      acc[j] = __builtin_amdgcn_mfma_f32_16x16x32_bf16(af[0], bfr[j][0], acc[j], 0, 0, 0);
      acc[j] = __builtin_amdgcn_mfma_f32_16x16x32_bf16(af[1], bfr[j][1], acc[j], 0, 0, 0);
    }
    __builtin_amdgcn_s_barrier();
  }
#undef STG2

  const int er = (lane >> 4) * 4, ec = lane & 15;
#pragma unroll
  for (int j = 0; j < 2; ++j) {
    const int col = n0 + wn + j * 16 + ec;
    const float b = bias[col];
#pragma unroll
    for (int rr = 0; rr < 4; ++rr) {
      const int row = m0 + wm + er + rr;
      C[(size_t)row * N + col] = acc[j][rr] + b;
    }
  }
}

// ---------------- MFMA flash attention, 4-way key split, KVBLK=32 ----------------
// Block = (16-pos tile, head). 256 threads = 4 waves, each owning every 4th 32-key
// chunk. Two 16-key subtiles are packed per iteration: subtile A fills MFMA k-slots
// quad*8+0..3 (pf[0..3]/vf[0..3]), subtile B fills quad*8+4..7 -> PV MFMAs run at
// full K=32 utilization (half the PV MFMA count, shuffles and rescales of KVBLK=16).
// Self-healing of all-invalid chunks is preserved (exp(0) garbage wiped by corr=0 at
// the first real chunk, or by c_w=0 at merge). grid (129, 8).
__global__ __launch_bounds__(256, 4) void attn_mfma(const unsigned short* __restrict__ qkv,
                                                    const int* __restrict__ glist,
                                                    const int* __restrict__ gcnt,
                                                    unsigned short* __restrict__ O) {
  __shared__ __align__(16) int list[192];
  __shared__ __align__(16) unsigned short Vlds[4][32 * 72];
  __shared__ __align__(16) float mOd[3][16][72];
  __shared__ float mM[3][16], mL[3][16];
  __shared__ int cntS;

  const int tid  = threadIdx.x;
  const int head = blockIdx.y;    // 0..7

  if (blockIdx.x == 128) {  // output row 0 = V(token 0)
    if (tid < 64) O[head * 64 + tid] = qkv[1024 + head * 64 + tid];
    return;
  }
  const int pt = blockIdx.x;
  const int f  = pt >> 6;
  const int hh = (pt >> 1) & 31;
  const int w0 = (pt & 1) << 4;
  const int base_i = (f << 10) | (hh << 5) | w0;

  if (tid < 192) list[tid] = glist[pt * 192 + tid];
  if (tid == 0) cntS = gcnt[pt];
  __syncthreads();
  const int nsub32 = (cntS + 31) >> 5;

  const int lane = tid & 63;
  const int wave = tid >> 6;      // chunk owner 0..3
  const int quad = lane >> 4;
  const int ec   = lane & 15;

  const int i_q = base_i + ec;
  const int tq  = min(i_q + 1, 2047);
  const unsigned short* qrow = qkv + (size_t)tq * QKVP + head * 64 + quad * 8;
  const bf16x8 qb0 = *(const bf16x8*)(qrow);
  const bf16x8 qb1 = *(const bf16x8*)(qrow + 32);

  unsigned short* vbuf = &Vlds[wave][0];

  f32x4 Od[4] = {{0,0,0,0},{0,0,0,0},{0,0,0,0},{0,0,0,0}};
  float m = -1e30f, l = 0.0f;

  for (int sub = wave; sub < nsub32; sub += 4) {
    const int base = sub * 32;
    const int tokA = list[base + ec];
    const int tokB = list[base + 16 + ec];
    const int4 tkvA = *(const int4*)&list[base + quad * 4];
    const int4 tkvB = *(const int4*)&list[base + 16 + quad * 4];

    // K/V rows for key index ec of each half, coalesced bf16x8 loads
    const int tA = (tokA > 2047) ? 0 : tokA;
    const int tB = (tokB > 2047) ? 0 : tokB;
    const unsigned short* krA = qkv + (size_t)tA * QKVP + 512 + head * 64 + quad * 8;
    const unsigned short* vrA = qkv + (size_t)tA * QKVP + 1024 + head * 64 + quad * 8;
    const unsigned short* krB = qkv + (size_t)tB * QKVP + 512 + head * 64 + quad * 8;
    const unsigned short* vrB = qkv + (size_t)tB * QKVP + 1024 + head * 64 + quad * 8;
    const bf16x8 kA0 = *(const bf16x8*)(krA);
    const bf16x8 kA1 = *(const bf16x8*)(krA + 32);
    const bf16x8 kB0 = *(const bf16x8*)(krB);
    const bf16x8 kB1 = *(const bf16x8*)(krB + 32);
    const bf16x8 vA0 = *(const bf16x8*)(vrA);
    const bf16x8 vA1 = *(const bf16x8*)(vrA + 32);
    const bf16x8 vB0 = *(const bf16x8*)(vrB);
    const bf16x8 vB1 = *(const bf16x8*)(vrB + 32);

    f32x4 SA = {0, 0, 0, 0}, SB = {0, 0, 0, 0};
    SA = __builtin_amdgcn_mfma_f32_16x16x32_bf16(kA0, qb0, SA, 0, 0, 0);
    SA = __builtin_amdgcn_mfma_f32_16x16x32_bf16(kA1, qb1, SA, 0, 0, 0);
    SB = __builtin_amdgcn_mfma_f32_16x16x32_bf16(kB0, qb0, SB, 0, 0, 0);
    SB = __builtin_amdgcn_mfma_f32_16x16x32_bf16(kB1, qb1, SB, 0, 0, 0);

    // stage both 16-row V subtiles: rows 0..15 = half A, 16..31 = half B
    *(bf16x8*)&vbuf[ec * 72 + quad * 8]             = vA0;
    *(bf16x8*)&vbuf[ec * 72 + 32 + quad * 8]        = vA1;
    *(bf16x8*)&vbuf[(16 + ec) * 72 + quad * 8]      = vB0;
    *(bf16x8*)&vbuf[(16 + ec) * 72 + 32 + quad * 8] = vB1;

    const int tka[4] = {tkvA.x, tkvA.y, tkvA.z, tkvA.w};
    const int tkb[4] = {tkvB.x, tkvB.y, tkvB.z, tkvB.w};
    float Sm[8];
#pragma unroll
    for (int r = 0; r < 4; ++r) {
      {
        const int tok = tka[r];
        const int idx = tok - 1;
        const bool v = (tok == 0) ||
                       ((idx <= i_q) && ((unsigned)((idx & 31) - (w0 + ec) + 2) <= 4u));
        Sm[r] = v ? SA[r] * 0.125f : -1e30f;
      }
      {
        const int tok = tkb[r];
        const int idx = tok - 1;
        const bool v = (tok == 0) ||
                       ((idx <= i_q) && ((unsigned)((idx & 31) - (w0 + ec) + 2) <= 4u));
        Sm[4 + r] = v ? SB[r] * 0.125f : -1e30f;
      }
    }
    float mx = fmaxf(fmaxf(fmaxf(Sm[0], Sm[1]), fmaxf(Sm[2], Sm[3])),
                     fmaxf(fmaxf(Sm[4], Sm[5]), fmaxf(Sm[6], Sm[7])));
    mx = fmaxf(mx, __shfl_xor(mx, 16, 64));
    mx = fmaxf(mx, __shfl_xor(mx, 32, 64));
    const float mn = fmaxf(m, mx);
    const float corr = __expf(m - mn);
    m = mn;
    float p[8];
#pragma unroll
    for (int i = 0; i < 8; ++i) p[i] = __expf(Sm[i] - mn);
    float rs = ((p[0] + p[1]) + (p[2] + p[3])) + ((p[4] + p[5]) + (p[6] + p[7]));
    rs += __shfl_xor(rs, 16, 64);
    rs += __shfl_xor(rs, 32, 64);
    l = l * corr + rs;

    bf16x8 pf;
#pragma unroll
    for (int i = 0; i < 8; ++i) pf[i] = (short)f2b(p[i]);

    // vf gather: slots 0..3 = keys quad*4+j (half A), 4..7 = keys 16+quad*4+j (half B)
#pragma unroll
    for (int dt = 0; dt < 4; ++dt) {
      bf16x8 vf;
#pragma unroll
      for (int j = 0; j < 4; ++j) {
        vf[j]     = (short)vbuf[(quad * 4 + j) * 72 + dt * 16 + ec];
        vf[4 + j] = (short)vbuf[(16 + quad * 4 + j) * 72 + dt * 16 + ec];
      }
#pragma unroll
      for (int r = 0; r < 4; ++r) Od[dt][r] *= corr;
      Od[dt] = __builtin_amdgcn_mfma_f32_16x16x32_bf16(vf, pf, Od[dt], 0, 0, 0);
    }
  }

  // merge the four key-chunk owners of this head
  if (wave > 0) {
#pragma unroll
    for (int dt = 0; dt < 4; ++dt)
      *(f32x4*)&mOd[wave - 1][ec][dt * 16 + quad * 4] = Od[dt];
    if (quad == 0) { mM[wave - 1][ec] = m; mL[wave - 1][ec] = l; }
  }
  __syncthreads();
  if (wave == 0 && i_q <= 2046) {
    const float m1 = mM[0][ec], m2 = mM[1][ec], m3 = mM[2][ec];
    const float mm = fmaxf(fmaxf(m, m1), fmaxf(m2, m3));
    const float c0 = __expf(m - mm);
    const float c1 = __expf(m1 - mm);
    const float c2 = __expf(m2 - mm);
    const float c3 = __expf(m3 - mm);
    const float rl = 1.0f / (l * c0 + mL[0][ec] * c1 + mL[1][ec] * c2 + mL[2][ec] * c3);
    unsigned short* ob = O + (size_t)(i_q + 1) * 512 + head * 64 + quad * 4;
#pragma unroll
    for (int dt = 0; dt < 4; ++dt) {
      const f32x4 o1 = *(const f32x4*)&mOd[0][ec][dt * 16 + quad * 4];
      const f32x4 o2 = *(const f32x4*)&mOd[1][ec][dt * 16 + quad * 4];
      const f32x4 o3 = *(const f32x4*)&mOd[2][ec][dt * 16 + quad * 4];
      ushort4 u;
      u.x = f2b((Od[dt][0] * c0 + o1[0] * c1 + o2[0] * c2 + o3[0] * c3) * rl);
      u.y = f2b((Od[dt][1] * c0 + o1[1] * c1 + o2[1] * c2 + o3[1] * c3) * rl);
      u.z = f2b((Od[dt][2] * c0 + o1[2] * c1 + o2[2] * c2 + o3[2] * c3) * rl);
      u.w = f2b((Od[dt][3] * c0 + o1[3] * c1 + o2[3] * c2 + o3[3] * c3) * rl);
      *(ushort4*)(ob + dt * 16) = u;
    }
  }
}

// ---------------- launch ----------------

extern "C" void kernel_launch(void* const* d_in, const int* in_sizes, int n_in,
                              void* d_out, int out_size, void* d_ws, size_t ws_size,
                              hipStream_t stream) {
  const float* x     = (const float*)d_in[0];
  const float* w_qkv = (const float*)d_in[1];
  const float* w_out = (const float*)d_in[2];
  const float* b_out = (const float*)d_in[3];
  float* out = (float*)d_out;

  char* ws = (char*)d_ws;
  unsigned short* qkvb  = (unsigned short*)(ws);              // 2048x1536 bf16
  unsigned short* wqkvT = (unsigned short*)(ws + 6291456);    // 1536x512
  unsigned short* woutT = (unsigned short*)(ws + 7864320);    // 512x512
  unsigned short* Ob    = (unsigned short*)(ws + 8388608);    // 2048x512
  unsigned short* xb    = (unsigned short*)(ws + 10485760);   // 2048x512
  int*            glist = (int*)(ws + 12582912);              // 128x192 int
  int*            gcnt  = (int*)(ws + 12681216);              // 128 int

  hipLaunchKernelGGL(prep, dim3(2176), dim3(256), 0, stream,
                     w_qkv, w_out, x, wqkvT, woutT, xb, glist, gcnt);

  hipLaunchKernelGGL(gemm_qkv, dim3(768), dim3(256), 0, stream, xb, wqkvT, qkvb);

  hipLaunchKernelGGL(attn_mfma, dim3(129, 8), dim3(256), 0, stream, qkvb, glist, gcnt, Ob);

  hipLaunchKernelGGL(gemm_out, dim3(512), dim3(256), 0, stream, Ob, woutT, b_out, out);
}

// Round 8
// 88.071 us; speedup vs baseline: 1.0237x; 1.0237x over previous
//
#include <hip/hip_runtime.h>
#include <hip/hip_bf16.h>

#define NTOK  2048          // F*H*W = 2*32*32
#define INNER 512
#define KDIM  512
#define QKVP  1536          // qkv row pitch (bf16 elems)

typedef __attribute__((ext_vector_type(8))) short bf16x8;
typedef __attribute__((ext_vector_type(4))) float f32x4;

// fp32 -> bf16 bits, round-to-nearest-even
__device__ __forceinline__ unsigned short f2b(float f) {
  unsigned int u = __float_as_uint(f);
  return (unsigned short)((u + 0x7FFFu + ((u >> 16) & 1u)) >> 16);
}

// async global->LDS, 16 bytes per lane (wave-linear LDS mapping required)
__device__ __forceinline__ void async_copy16(const unsigned short* g, unsigned short* l) {
  __builtin_amdgcn_global_load_lds((const __attribute__((address_space(1))) void*)g,
                                   (__attribute__((address_space(3))) void*)l, 16, 0, 0);
}

// ---------------- prep: weight transposes + x conversion + neighbor lists ----------------
// blocks 0..767:    w_qkv [512][1536] -> wqkvT [1536][512] bf16
// blocks 768..1023: w_out [512][512]  -> woutT [512][512]  bf16
// blocks 1024..1151: packed causal key list for tile pt = b-1024
// blocks 1152..2175: x fp32 -> xb bf16 (4 elems/thread)
__global__ __launch_bounds__(256) void prep(const float* __restrict__ w_qkv,
                                            const float* __restrict__ w_out,
                                            const float* __restrict__ x,
                                            unsigned short* __restrict__ wqkvT,
                                            unsigned short* __restrict__ woutT,
                                            unsigned short* __restrict__ xb,
                                            int* __restrict__ glist,
                                            int* __restrict__ gcnt) {
  __shared__ float tile[32][33];
  __shared__ int list[192];
  __shared__ int cntS;
  const int tid = threadIdx.x;
  int b = blockIdx.x;

  if (b >= 1152) {  // x conversion
    const int i = (b - 1152) * 1024 + tid * 4;
    float4 v = *(const float4*)(x + i);
    ushort4 o;
    o.x = f2b(v.x); o.y = f2b(v.y); o.z = f2b(v.z); o.w = f2b(v.w);
    *(ushort4*)(xb + i) = o;
    return;
  }

  if (b < 1024) {  // weight transpose
    const float* in; unsigned short* out; int K, N, bx, by;
    if (b < 768) { in = w_qkv; out = wqkvT; K = 512; N = 1536; bx = b % 48; by = b / 48; }
    else { int bb = b - 768; in = w_out; out = woutT; K = 512; N = 512; bx = bb & 15; by = bb >> 4; }
    const int k0 = by * 32, n0 = bx * 32;
    const int r = tid >> 3, c4 = (tid & 7) * 4;
    float4 v = *(const float4*)(in + (size_t)(k0 + r) * N + n0 + c4);
    tile[r][c4 + 0] = v.x; tile[r][c4 + 1] = v.y;
    tile[r][c4 + 2] = v.z; tile[r][c4 + 3] = v.w;
    __syncthreads();
    ushort4 o;
    o.x = f2b(tile[c4 + 0][r]);
    o.y = f2b(tile[c4 + 1][r]);
    o.z = f2b(tile[c4 + 2][r]);
    o.w = f2b(tile[c4 + 3][r]);
    *(ushort4*)(out + (size_t)(n0 + r) * K + k0 + c4) = o;
    return;
  }

  // ---- neighbor list for one 16-w tile ----
  const int pt = b - 1024;
  const int f  = pt >> 6;
  const int hh = (pt >> 1) & 31;
  const int w0 = (pt & 1) << 4;

  if (tid < 192) list[tid] = 0x7FFFFFFF;
  if (tid == 0) { list[0] = 0; cntS = 1; }
  __syncthreads();
  if (tid >= 1 && tid <= 160) {
    int cc = tid - 1;
    int p = cc / 20, wo = cc - p * 20;
    int ff = (p < 5) ? 0 : 1;
    int h2 = hh - 2 + ((p < 5) ? p : (p - 5));
    bool ok = (p < 5) ? ((f == 1) ? (h2 >= 0 && h2 <= 31) : (p <= 2 && h2 >= 0))
                      : (f == 1 && h2 >= 0);
    if (ok) {
      bool diag = (ff == f) && (h2 == hh);
      int wlo = max(0, w0 - 2);
      int whi = min(31, diag ? (w0 + 15) : (w0 + 17));
      int w2 = wlo + wo;
      if (w2 <= whi) {
        int pos = atomicAdd(&cntS, 1);
        list[pos] = ((ff << 10) | (h2 << 5) | w2) + 1;
      }
    }
  }
  __syncthreads();
  if (tid < 192) glist[pt * 192 + tid] = list[tid];
  if (tid == 0) gcnt[pt] = cntS;
}

// ---------------- GEMM1: qkv = xb @ wqkvT^T -> bf16 ----------------
// BM=64, BN=64, BK=64; 2-deep double-buffered global_load_lds pipeline with counted
// vmcnt(4) (never 0 mid-loop): iteration it+1's 4 staging loads stay in flight across
// the barrier while iteration it computes. Raw s_barrier avoids the compiler's
// vmcnt(0) drain that __syncthreads would force. grid 24x32 = 768 blocks.
__global__ __launch_bounds__(256, 4) void gemm_qkv(const unsigned short* __restrict__ A,
                                                   const unsigned short* __restrict__ Bt,
                                                   unsigned short* __restrict__ C) {
  constexpr int N = 1536, K = 512;
  __shared__ __align__(16) unsigned short As[2][2][64 * 32];   // [buf][half]
  __shared__ __align__(16) unsigned short Bs[2][2][64 * 32];
  const int tid = threadIdx.x, lane = tid & 63, wave = tid >> 6;
  const int m0 = blockIdx.y * 64, n0 = blockIdx.x * 64;
  const int wm = (wave >> 1) * 32, wn = (wave & 1) * 32;
  const int li = tid * 8, r = li >> 5, c = li & 31;   // 64x32 sub-tile: 8 elems/thread
  const int fr = lane & 15, fk = (lane >> 4) * 8;

  f32x4 acc[2][2] = {};

#define STG1(buf, kk)                                                              \
  do {                                                                             \
    async_copy16(A  + (size_t)(m0 + r) * K + (kk) + c,      &As[buf][0][li]);      \
    async_copy16(A  + (size_t)(m0 + r) * K + (kk) + 32 + c, &As[buf][1][li]);      \
    async_copy16(Bt + (size_t)(n0 + r) * K + (kk) + c,      &Bs[buf][0][li]);      \
    async_copy16(Bt + (size_t)(n0 + r) * K + (kk) + 32 + c, &Bs[buf][1][li]);      \
  } while (0)

  STG1(0, 0);
#pragma unroll
  for (int it = 0; it < 8; ++it) {
    const int cur = it & 1;
    if (it < 7) {
      STG1(cur ^ 1, (it + 1) * 64);
      asm volatile("s_waitcnt vmcnt(4)" ::: "memory");   // drain tile it, keep it+1 in flight
    } else {
      asm volatile("s_waitcnt vmcnt(0)" ::: "memory");
    }
    __builtin_amdgcn_s_barrier();        // all waves' tile-it stages now landed
    __builtin_amdgcn_sched_barrier(0);   // don't hoist ds_reads above the wait
    bf16x8 af[2][2], bfr[2][2];
#pragma unroll
    for (int h = 0; h < 2; ++h) {
#pragma unroll
      for (int i = 0; i < 2; ++i) af[i][h]  = *(const bf16x8*)&As[cur][h][(wm + i * 16 + fr) * 32 + fk];
#pragma unroll
      for (int j = 0; j < 2; ++j) bfr[j][h] = *(const bf16x8*)&Bs[cur][h][(wn + j * 16 + fr) * 32 + fk];
    }
#pragma unroll
    for (int i = 0; i < 2; ++i)
#pragma unroll
      for (int j = 0; j < 2; ++j) {
        acc[i][j] = __builtin_amdgcn_mfma_f32_16x16x32_bf16(af[i][0], bfr[j][0], acc[i][j], 0, 0, 0);
        acc[i][j] = __builtin_amdgcn_mfma_f32_16x16x32_bf16(af[i][1], bfr[j][1], acc[i][j], 0, 0, 0);
      }
    __builtin_amdgcn_s_barrier();        // all reads of buf cur done before it+2 overwrites
  }
#undef STG1

  const int er = (lane >> 4) * 4, ec = lane & 15;
#pragma unroll
  for (int i = 0; i < 2; ++i)
#pragma unroll
    for (int j = 0; j < 2; ++j) {
      const int col = n0 + wn + j * 16 + ec;
#pragma unroll
      for (int rr = 0; rr < 4; ++rr) {
        const int row = m0 + wm + i * 16 + er + rr;
        C[(size_t)row * N + col] = f2b(acc[i][j][rr]);
      }
    }
}

// ---------------- GEMM2: out = Ob @ woutT^T + bias -> fp32 ----------------
// BM=32, BN=64, BK=64; same 2-deep counted-vmcnt pipeline. Staging is asymmetric
// (waves 0,1 issue 4 loads/iter, waves 2,3 issue 2) so the counted wait is
// wave-uniform-branched: vmcnt(4) vs vmcnt(2). grid 8x64 = 512 blocks.
__global__ __launch_bounds__(256, 4) void gemm_out(const unsigned short* __restrict__ A,
                                                   const unsigned short* __restrict__ Bt,
                                                   const float* __restrict__ bias,
                                                   float* __restrict__ C) {
  constexpr int N = 512, K = 512;
  __shared__ __align__(16) unsigned short As[2][2][32 * 32];
  __shared__ __align__(16) unsigned short Bs[2][2][64 * 32];
  const int tid = threadIdx.x, lane = tid & 63, wave = tid >> 6;
  const int m0 = blockIdx.y * 32, n0 = blockIdx.x * 64;
  const int wm = (wave >> 1) * 16, wn = (wave & 1) * 32;
  const int li = tid * 8, r = li >> 5, c = li & 31;
  const int fr = lane & 15, fk = (lane >> 4) * 8;

  f32x4 acc[2] = {};

#define STG2(buf, kk)                                                               \
  do {                                                                              \
    if (tid < 128) {                                                                \
      async_copy16(A + (size_t)(m0 + r) * K + (kk) + c,      &As[buf][0][li]);      \
      async_copy16(A + (size_t)(m0 + r) * K + (kk) + 32 + c, &As[buf][1][li]);      \
    }                                                                               \
    async_copy16(Bt + (size_t)(n0 + r) * K + (kk) + c,      &Bs[buf][0][li]);       \
    async_copy16(Bt + (size_t)(n0 + r) * K + (kk) + 32 + c, &Bs[buf][1][li]);       \
  } while (0)

  STG2(0, 0);
#pragma unroll
  for (int it = 0; it < 8; ++it) {
    const int cur = it & 1;
    if (it < 7) {
      STG2(cur ^ 1, (it + 1) * 64);
      if (wave < 2) asm volatile("s_waitcnt vmcnt(4)" ::: "memory");
      else          asm volatile("s_waitcnt vmcnt(2)" ::: "memory");
    } else {
      asm volatile("s_waitcnt vmcnt(0)" ::: "memory");
    }
    __builtin_amdgcn_s_barrier();
    __builtin_amdgcn_sched_barrier(0);
    bf16x8 af[2], bfr[2][2];
#pragma unroll
    for (int h = 0; h < 2; ++h) {
      af[h] = *(const bf16x8*)&As[cur][h][(wm + fr) * 32 + fk];
#pragma unroll
      for (int j = 0; j < 2; ++j) bfr[j][h] = *(const bf16x8*)&Bs[cur][h][(wn + j * 16 + fr) * 32 + fk];
    }
#pragma unroll
    for (int j = 0; j < 2; ++j) {
      acc[j] = __builtin_amdgcn_mfma_f32_16x16x32_bf16(af[0], bfr[j][0], acc[j], 0, 0, 0);
      acc[j] = __builtin_amdgcn_mfma_f32_16x16x32_bf16(af[1], bfr[j][1], acc[j], 0, 0, 0);
    }
    __builtin_amdgcn_s_barrier();
  }
#undef STG2

  const int er = (lane >> 4) * 4, ec = lane & 15;
#pragma unroll
  for (int j = 0; j < 2; ++j) {
    const int col = n0 + wn + j * 16 + ec;
    const float b = bias[col];
#pragma unroll
    for (int rr = 0; rr < 4; ++rr) {
      const int row = m0 + wm + er + rr;
      C[(size_t)row * N + col] = acc[j][rr] + b;
    }
  }
}

// ---------------- MFMA flash attention, 4-way key split, LDS-staged V ----------------
// Block = (16-pos tile, head). 256 threads = 4 waves = 4 key-quarters of one head.
// grid (129, 8) = 1032 blocks -> 4 blocks/CU = 16 waves/CU.
__global__ __launch_bounds__(256, 4) void attn_mfma(const unsigned short* __restrict__ qkv,
                                                    const int* __restrict__ glist,
                                                    const int* __restrict__ gcnt,
                                                    unsigned short* __restrict__ O) {
  __shared__ __align__(16) int list[192];
  __shared__ __align__(16) unsigned short Vlds[4][16 * 72];
  __shared__ __align__(16) float mOd[3][16][72];
  __shared__ float mM[3][16], mL[3][16];
  __shared__ int cntS;

  const int tid  = threadIdx.x;
  const int head = blockIdx.y;    // 0..7

  if (blockIdx.x == 128) {  // output row 0 = V(token 0)
    if (tid < 64) O[head * 64 + tid] = qkv[1024 + head * 64 + tid];
    return;
  }
  const int pt = blockIdx.x;
  const int f  = pt >> 6;
  const int hh = (pt >> 1) & 31;
  const int w0 = (pt & 1) << 4;
  const int base_i = (f << 10) | (hh << 5) | w0;

  if (tid < 192) list[tid] = glist[pt * 192 + tid];
  if (tid == 0) cntS = gcnt[pt];
  __syncthreads();
  const int nsub = (cntS + 15) >> 4;

  const int lane = tid & 63;
  const int wave = tid >> 6;      // key-quarter 0..3
  const int quad = lane >> 4;
  const int ec   = lane & 15;

  const int i_q = base_i + ec;
  const int tq  = min(i_q + 1, 2047);
  const unsigned short* qrow = qkv + (size_t)tq * QKVP + head * 64 + quad * 8;
  const bf16x8 qb0 = *(const bf16x8*)(qrow);
  const bf16x8 qb1 = *(const bf16x8*)(qrow + 32);

  unsigned short* vbuf = &Vlds[wave][0];

  f32x4 Od[4] = {{0,0,0,0},{0,0,0,0},{0,0,0,0},{0,0,0,0}};
  float m = -1e30f, l = 0.0f;

  for (int sub = wave; sub < nsub; sub += 4) {
    const int base = sub * 16;
    const int tok_e = list[base + ec];
    const int4 tokv = *(const int4*)&list[base + quad * 4];
    const int tk[4] = {tokv.x, tokv.y, tokv.z, tokv.w};

    // key index ec: K row for QK^T (regs) and V row (staged to LDS), both coalesced
    const int t0 = (tok_e > 2047) ? 0 : tok_e;
    const unsigned short* kr = qkv + (size_t)t0 * QKVP + 512 + head * 64 + quad * 8;
    const unsigned short* vr = qkv + (size_t)t0 * QKVP + 1024 + head * 64 + quad * 8;
    const bf16x8 kf0 = *(const bf16x8*)(kr);
    const bf16x8 kf1 = *(const bf16x8*)(kr + 32);
    const bf16x8 vs0 = *(const bf16x8*)(vr);
    const bf16x8 vs1 = *(const bf16x8*)(vr + 32);

    f32x4 S = {0, 0, 0, 0};
    S = __builtin_amdgcn_mfma_f32_16x16x32_bf16(kf0, qb0, S, 0, 0, 0);
    S = __builtin_amdgcn_mfma_f32_16x16x32_bf16(kf1, qb1, S, 0, 0, 0);

    // stage V subtile: row = key index (ec), cols d = quad*8..+7 and 32+quad*8..+7
    *(bf16x8*)&vbuf[ec * 72 + quad * 8]      = vs0;
    *(bf16x8*)&vbuf[ec * 72 + 32 + quad * 8] = vs1;

    float Sm[4];
#pragma unroll
    for (int r = 0; r < 4; ++r) {
      const int tok = tk[r];
      const int idx = tok - 1;
      const bool v = (tok == 0) ||
                     ((idx <= i_q) && ((unsigned)((idx & 31) - (w0 + ec) + 2) <= 4u));
      Sm[r] = v ? S[r] * 0.125f : -1e30f;
    }
    float mx = fmaxf(fmaxf(Sm[0], Sm[1]), fmaxf(Sm[2], Sm[3]));
    mx = fmaxf(mx, __shfl_xor(mx, 16, 64));
    mx = fmaxf(mx, __shfl_xor(mx, 32, 64));
    const float mn = fmaxf(m, mx);
    const float corr = __expf(m - mn);
    m = mn;
    const float p0 = __expf(Sm[0] - mn);
    const float p1 = __expf(Sm[1] - mn);
    const float p2 = __expf(Sm[2] - mn);
    const float p3 = __expf(Sm[3] - mn);
    float rs = (p0 + p1) + (p2 + p3);
    rs += __shfl_xor(rs, 16, 64);
    rs += __shfl_xor(rs, 32, 64);
    l = l * corr + rs;

    bf16x8 pf;
    pf[0] = (short)f2b(p0); pf[1] = (short)f2b(p1);
    pf[2] = (short)f2b(p2); pf[3] = (short)f2b(p3);
    pf[4] = 0; pf[5] = 0; pf[6] = 0; pf[7] = 0;

    // vf gather from LDS: lane (quad,ec) needs V[key quad*4+j][dt*16+ec]
#pragma unroll
    for (int dt = 0; dt < 4; ++dt) {
      bf16x8 vf;
#pragma unroll
      for (int j = 0; j < 4; ++j) vf[j] = (short)vbuf[(quad * 4 + j) * 72 + dt * 16 + ec];
      vf[4] = 0; vf[5] = 0; vf[6] = 0; vf[7] = 0;
#pragma unroll
      for (int r = 0; r < 4; ++r) Od[dt][r] *= corr;
      Od[dt] = __builtin_amdgcn_mfma_f32_16x16x32_bf16(vf, pf, Od[dt], 0, 0, 0);
    }
  }

  // merge the four key-quarters of this head
  if (wave > 0) {
#pragma unroll
    for (int dt = 0; dt < 4; ++dt)
      *(f32x4*)&mOd[wave - 1][ec][dt * 16 + quad * 4] = Od[dt];
    if (quad == 0) { mM[wave - 1][ec] = m; mL[wave - 1][ec] = l; }
  }
  __syncthreads();
  if (wave == 0 && i_q <= 2046) {
    const float m1 = mM[0][ec], m2 = mM[1][ec], m3 = mM[2][ec];
    const float mm = fmaxf(fmaxf(m, m1), fmaxf(m2, m3));
    const float c0 = __expf(m - mm);
    const float c1 = __expf(m1 - mm);
    const float c2 = __expf(m2 - mm);
    const float c3 = __expf(m3 - mm);
    const float rl = 1.0f / (l * c0 + mL[0][ec] * c1 + mL[1][ec] * c2 + mL[2][ec] * c3);
    unsigned short* ob = O + (size_t)(i_q + 1) * 512 + head * 64 + quad * 4;
#pragma unroll
    for (int dt = 0; dt < 4; ++dt) {
      const f32x4 o1 = *(const f32x4*)&mOd[0][ec][dt * 16 + quad * 4];
      const f32x4 o2 = *(const f32x4*)&mOd[1][ec][dt * 16 + quad * 4];
      const f32x4 o3 = *(const f32x4*)&mOd[2][ec][dt * 16 + quad * 4];
      ushort4 u;
      u.x = f2b((Od[dt][0] * c0 + o1[0] * c1 + o2[0] * c2 + o3[0] * c3) * rl);
      u.y = f2b((Od[dt][1] * c0 + o1[1] * c1 + o2[1] * c2 + o3[1] * c3) * rl);
      u.z = f2b((Od[dt][2] * c0 + o1[2] * c1 + o2[2] * c2 + o3[2] * c3) * rl);
      u.w = f2b((Od[dt][3] * c0 + o1[3] * c1 + o2[3] * c2 + o3[3] * c3) * rl);
      *(ushort4*)(ob + dt * 16) = u;
    }
  }
}

// ---------------- launch ----------------

extern "C" void kernel_launch(void* const* d_in, const int* in_sizes, int n_in,
                              void* d_out, int out_size, void* d_ws, size_t ws_size,
                              hipStream_t stream) {
  const float* x     = (const float*)d_in[0];
  const float* w_qkv = (const float*)d_in[1];
  const float* w_out = (const float*)d_in[2];
  const float* b_out = (const float*)d_in[3];
  float* out = (float*)d_out;

  char* ws = (char*)d_ws;
  unsigned short* qkvb  = (unsigned short*)(ws);              // 2048x1536 bf16
  unsigned short* wqkvT = (unsigned short*)(ws + 6291456);    // 1536x512
  unsigned short* woutT = (unsigned short*)(ws + 7864320);    // 512x512
  unsigned short* Ob    = (unsigned short*)(ws + 8388608);    // 2048x512
  unsigned short* xb    = (unsigned short*)(ws + 10485760);   // 2048x512
  int*            glist = (int*)(ws + 12582912);              // 128x192 int
  int*            gcnt  = (int*)(ws + 12681216);              // 128 int

  hipLaunchKernelGGL(prep, dim3(2176), dim3(256), 0, stream,
                     w_qkv, w_out, x, wqkvT, woutT, xb, glist, gcnt);

  hipLaunchKernelGGL(gemm_qkv, dim3(24, 32), dim3(256), 0, stream, xb, wqkvT, qkvb);

  hipLaunchKernelGGL(attn_mfma, dim3(129, 8), dim3(256), 0, stream, qkvb, glist, gcnt, Ob);

  hipLaunchKernelGGL(gemm_out, dim3(8, 64), dim3(256), 0, stream, Ob, woutT, b_out, out);
}